// Round 8
// baseline (17424.524 us; speedup 1.0000x reference)
//
#include <hip/hip_runtime.h>

#define BB   512
#define SS   256
#define NIN  128
#define DH   1024
#define DC   1152   // NIN + DH
#define NOUT 128
#define EPSV 1e-5f

typedef _Float16 f16;
typedef _Float16 f16x8 __attribute__((ext_vector_type(8)));
typedef _Float16 f16x4 __attribute__((ext_vector_type(4)));
typedef float    f32x4 __attribute__((ext_vector_type(4)));

__device__ __forceinline__ float sigmoid_(float x) { return 1.0f / (1.0f + __expf(-x)); }
__device__ __forceinline__ float tanh_(float x) {
    x = fminf(fmaxf(x, -15.0f), 15.0f);
    float e = __expf(2.0f * x);
    return (e - 1.0f) / (e + 1.0f);
}

// ---------------- weight conversion (fp32 -> fp16), once per launch ----------------
__global__ void k_convert(const float* __restrict__ Wu, const float* __restrict__ Wr,
                          const float* __restrict__ Wh_, const float* __restrict__ Wo_,
                          f16* __restrict__ wur, f16* __restrict__ wh, f16* __restrict__ wo)
{
    const int stride = gridDim.x * blockDim.x;
    const int i0 = blockIdx.x * blockDim.x + threadIdx.x;
    for (int i = i0; i < 2048 * 1152 / 4; i += stride) {
        int base = i * 4;
        int n = base / 1152, k = base % 1152;
        const float* src = (n < 1024) ? (Wu + (size_t)n * 1152 + k) : (Wr + (size_t)(n - 1024) * 1152 + k);
        float4 v = *(const float4*)src;
        f16x4 o; o[0] = (f16)v.x; o[1] = (f16)v.y; o[2] = (f16)v.z; o[3] = (f16)v.w;
        *(f16x4*)(wur + base) = o;
    }
    for (int i = i0; i < 1024 * 1152 / 4; i += stride) {
        int base = i * 4;
        float4 v = *(const float4*)(Wh_ + base);
        f16x4 o; o[0] = (f16)v.x; o[1] = (f16)v.y; o[2] = (f16)v.z; o[3] = (f16)v.w;
        *(f16x4*)(wh + base) = o;
    }
    for (int i = i0; i < 128 * 1024 / 4; i += stride) {
        int base = i * 4;
        float4 v = *(const float4*)(Wo_ + base);
        f16x4 o; o[0] = (f16)v.x; o[1] = (f16)v.y; o[2] = (f16)v.z; o[3] = (f16)v.w;
        *(f16x4*)(wo + base) = o;
    }
}

// ---------------- init: combA=[x0,0], combB[0]=[x0,0], combB[1]=0, h32=0, stats=0, tickets=0 ----
__global__ void k_init(const float* __restrict__ X, f16* __restrict__ combA, f16* __restrict__ combB,
                       float* __restrict__ h32,
                       float* __restrict__ ssum_ur, float* __restrict__ ssq_ur,
                       float* __restrict__ ssum_c, float* __restrict__ ssq_c,
                       unsigned* __restrict__ urt, unsigned* __restrict__ ct)
{
    const int stride = gridDim.x * blockDim.x;
    const int i0 = blockIdx.x * blockDim.x + threadIdx.x;
    for (int i = i0; i < BB * DC / 4; i += stride) {
        int base = i * 4;
        int m = base / DC, k = base % DC;
        f16x4 o;
        if (k < NIN) {
            float4 v = *(const float4*)(X + (size_t)m * SS * NIN + k);  // s = 0
            o[0] = (f16)v.x; o[1] = (f16)v.y; o[2] = (f16)v.z; o[3] = (f16)v.w;
        } else {
            o[0] = (f16)0.f; o[1] = (f16)0.f; o[2] = (f16)0.f; o[3] = (f16)0.f;
        }
        *(f16x4*)(combA + base) = o;
        *(f16x4*)(combB + base) = o;                       // combB[0]
        f16x4 z; z[0] = (f16)0.f; z[1] = (f16)0.f; z[2] = (f16)0.f; z[3] = (f16)0.f;
        *(f16x4*)(combB + (size_t)BB * DC + base) = z;     // combB[1]
    }
    for (int i = i0; i < BB * DH / 4; i += stride)
        *(float4*)(h32 + i * 4) = make_float4(0.f, 0.f, 0.f, 0.f);
    for (int i = i0; i < 2 * 2048; i += stride) { ssum_ur[i] = 0.f; ssq_ur[i] = 0.f; }
    for (int i = i0; i < 2 * 1024; i += stride) { ssum_c[i] = 0.f; ssq_c[i] = 0.f; }
    for (int i = i0; i < 16; i += stride) { urt[i] = 0u; ct[i] = 0u; }
}

// ---------------- 64x64 GEMM job, 8 waves: 2x2 spatial (32x32) x 2-way K-split ----------------
// verified numerics (rounds 1-7).  C[64,64] = A[m0:64,K] * B[n0:64,K]^T
template<int KT, bool OEPI>
__device__ __forceinline__ void gemm_job(
    const f16* __restrict__ A, int lda, const f16* __restrict__ Bm,
    float* __restrict__ C, int ldc,
    float* __restrict__ ssum, float* __restrict__ ssq,
    const float* __restrict__ bo, float* __restrict__ outp, int so,
    int m0, int n0, f16 (*As)[64][72], f16 (*Bs)[64][72])
{
    constexpr int KH = KT / 2;
    constexpr int NC = KH / 64;
    const int tid  = threadIdx.x;
    const int lane = tid & 63;
    const int wave = tid >> 6;
    const int g    = tid >> 8;           // K-half group
    const int sq   = wave & 3, wm = sq >> 1, wn = sq & 1;
    const int t    = tid & 255;
    const int r0   = t >> 3, kg = t & 7;

    const f16* Ap  = A  + (size_t)(m0 + r0) * lda + g * KH + kg * 8;
    const f16* Ap2 = Ap + (size_t)32 * lda;
    const f16* Bp  = Bm + (size_t)(n0 + r0) * KT + g * KH + kg * 8;
    const f16* Bp2 = Bp + (size_t)32 * KT;

    f32x4 acc[2][2] = {};
    f16x8 pa0 = *(const f16x8*)Ap;
    f16x8 pa1 = *(const f16x8*)Ap2;
    f16x8 pb0 = *(const f16x8*)Bp;
    f16x8 pb1 = *(const f16x8*)Bp2;

    for (int c = 0; c < NC; ++c) {
        *(f16x8*)&As[g][r0][kg * 8]      = pa0;
        *(f16x8*)&As[g][r0 + 32][kg * 8] = pa1;
        *(f16x8*)&Bs[g][r0][kg * 8]      = pb0;
        *(f16x8*)&Bs[g][r0 + 32][kg * 8] = pb1;
        __syncthreads();
        if (c + 1 < NC) {
            pa0 = *(const f16x8*)(Ap  + (c + 1) * 64);
            pa1 = *(const f16x8*)(Ap2 + (c + 1) * 64);
            pb0 = *(const f16x8*)(Bp  + (c + 1) * 64);
            pb1 = *(const f16x8*)(Bp2 + (c + 1) * 64);
        }
#pragma unroll
        for (int ks = 0; ks < 2; ++ks) {
            const int kofs = ks * 32 + (lane >> 4) * 8;
            f16x8 a0 = *(const f16x8*)&As[g][wm * 32 + (lane & 15)][kofs];
            f16x8 a1 = *(const f16x8*)&As[g][wm * 32 + 16 + (lane & 15)][kofs];
            f16x8 b0 = *(const f16x8*)&Bs[g][wn * 32 + (lane & 15)][kofs];
            f16x8 b1 = *(const f16x8*)&Bs[g][wn * 32 + 16 + (lane & 15)][kofs];
            acc[0][0] = __builtin_amdgcn_mfma_f32_16x16x32_f16(a0, b0, acc[0][0], 0, 0, 0);
            acc[0][1] = __builtin_amdgcn_mfma_f32_16x16x32_f16(a0, b1, acc[0][1], 0, 0, 0);
            acc[1][0] = __builtin_amdgcn_mfma_f32_16x16x32_f16(a1, b0, acc[1][0], 0, 0, 0);
            acc[1][1] = __builtin_amdgcn_mfma_f32_16x16x32_f16(a1, b1, acc[1][1], 0, 0, 0);
        }
        __syncthreads();
    }

    // K-split reduction through LDS
    float* red = (float*)As;
    const int rbase = (sq * 64 + lane) * 20;
    if (g == 1) {
#pragma unroll
        for (int fm = 0; fm < 2; ++fm)
#pragma unroll
            for (int fn = 0; fn < 2; ++fn)
                *(f32x4*)&red[rbase + (fm * 2 + fn) * 4] = acc[fm][fn];
    }
    __syncthreads();
    if (g == 0) {
#pragma unroll
        for (int fm = 0; fm < 2; ++fm)
#pragma unroll
            for (int fn = 0; fn < 2; ++fn)
                acc[fm][fn] += *(const f32x4*)&red[rbase + (fm * 2 + fn) * 4];

#pragma unroll
        for (int fm = 0; fm < 2; ++fm) {
#pragma unroll
            for (int fn = 0; fn < 2; ++fn) {
                const int row = m0 + wm * 32 + fm * 16 + (lane >> 4) * 4;
                const int col = n0 + wn * 32 + fn * 16 + (lane & 15);
                if constexpr (OEPI) {
#pragma unroll
                    for (int i = 0; i < 4; ++i) {
                        float v = tanh_(acc[fm][fn][i] + bo[col]);
                        outp[(size_t)(row + i) * (SS * NOUT) + (size_t)so * NOUT + col] = v;
                    }
                } else {
#pragma unroll
                    for (int i = 0; i < 4; ++i)
                        C[(size_t)(row + i) * ldc + col] = acc[fm][fn][i];
                }
            }
        }
        if constexpr (!OEPI) {
#pragma unroll
            for (int fn = 0; fn < 2; ++fn) {
                float s1 = 0.f, s2 = 0.f;
#pragma unroll
                for (int fm = 0; fm < 2; ++fm)
#pragma unroll
                    for (int i = 0; i < 4; ++i) { float v = acc[fm][fn][i]; s1 += v; s2 += v * v; }
                s1 += __shfl_xor(s1, 16, 64); s1 += __shfl_xor(s1, 32, 64);
                s2 += __shfl_xor(s2, 16, 64); s2 += __shfl_xor(s2, 32, 64);
                if (lane < 16) {
                    const int col = n0 + wn * 32 + fn * 16 + lane;
                    atomicAdd(&ssum[col], s1);
                    atomicAdd(&ssq[col], s2);
                }
            }
        }
    }
}

// ---------------- launch 1: o(s-1) (16) + ur-GEMM (256) + last-block gate epilogue ----------------
__global__ __launch_bounds__(512, 2)
void k_uro(const f16* __restrict__ combA, const f16* __restrict__ Wur, const f16* __restrict__ Wo16,
           float* __restrict__ pre_ur,
           float* __restrict__ ssum, float* __restrict__ ssq,          // parity stats (u|r)
           f16* __restrict__ combB_par, const float* __restrict__ h32,
           const float* __restrict__ g_r, const float* __restrict__ be_r,
           const float* __restrict__ b_o, float* __restrict__ outp,
           unsigned* __restrict__ urt, int s)
{
    __shared__ __align__(16) f16 smem[2][2][64][72];
    __shared__ int lastFlag;
    const int b = blockIdx.x;
    if (b < 16) {                       // o(s-1): reads combA h-region = h_new(s-1)
        if (s == 0) return;
        const int m0 = (b >> 1) * 64, n0 = (b & 1) * 64;
        gemm_job<DH, true>(combA + NIN, DC, Wo16, nullptr, 0, nullptr, nullptr,
                           b_o, outp, s - 1, m0, n0, smem[0], smem[1]);
        return;
    }
    const int j = b - 16;
    const int m0 = (j >> 5) * 64, n0 = (j & 31) * 64;
    gemm_job<DC, false>(combA, DC, Wur, pre_ur, 2048, ssum, ssq,
                        nullptr, nullptr, 0, m0, n0, smem[0], smem[1]);
    if (n0 < 1024) return;              // only r-column groups run the gate epilogue
    const int gid = (n0 - 1024) >> 6;
    __syncthreads();                    // all stats atomics + pre_ur stores complete (vmcnt drain)
    if (threadIdx.x == 0) {
        __threadfence();                // release: flush this block's stores to coherence point
        unsigned n = __hip_atomic_fetch_add(&urt[gid], 1u, __ATOMIC_ACQ_REL, __HIP_MEMORY_SCOPE_AGENT);
        lastFlag = (n == (unsigned)(s * 8 + 7));   // monotonic ticket: 8 arrivals per step
    }
    __syncthreads();
    if (!lastFlag) return;
    __builtin_amdgcn_fence(__ATOMIC_ACQUIRE, "agent");  // invalidate stale cached peer data

    // gate epilogue for r-cols n0..n0+63: combB_par.h <- fp16(sigmoid(BN(pre_r)) * h)
    const int tid = threadIdx.x;
    const int hc0 = n0 - 1024;
    const int c4 = (tid & 15) * 4;
    const int rb = tid >> 4;            // 0..31
    float mu[4], rq[4], gg[4], bb[4];
#pragma unroll
    for (int q = 0; q < 4; ++q) {
        const int col = n0 + c4 + q;
        float m_ = ssum[col] * (1.0f / 512.0f);
        float v_ = fmaxf(ssq[col] * (1.0f / 512.0f) - m_ * m_, 0.f);
        mu[q] = m_; rq[q] = rsqrtf(v_ + EPSV);
        gg[q] = g_r[hc0 + c4 + q]; bb[q] = be_r[hc0 + c4 + q];
    }
#pragma unroll 4
    for (int rr = 0; rr < 16; ++rr) {
        const int row = rb + rr * 32;
        f32x4 p = *(const f32x4*)(pre_ur + (size_t)row * 2048 + n0 + c4);
        f32x4 h = *(const f32x4*)(h32 + (size_t)row * 1024 + hc0 + c4);
        f16x4 o;
#pragma unroll
        for (int q = 0; q < 4; ++q) {
            float r = sigmoid_(gg[q] * ((p[q] - mu[q]) * rq[q]) + bb[q]);
            o[q] = (f16)(r * h[q]);
        }
        *(f16x4*)(combB_par + (size_t)row * DC + NIN + hc0 + c4) = o;
    }
}

// ---------------- launch 2: c-GEMM (128) + last-block update epilogue ----------------
__global__ __launch_bounds__(512, 2)
void k_c(const f16* __restrict__ combB_par, const f16* __restrict__ Wh16,
         float* __restrict__ pre_c, float* __restrict__ sc_, float* __restrict__ qc_,
         const float* __restrict__ pre_ur,
         const float* __restrict__ su, const float* __restrict__ qu,   // ur stats (parity)
         float* __restrict__ h32, f16* __restrict__ combA, f16* __restrict__ combB_nxt,
         float* __restrict__ z_su, float* __restrict__ z_qu,
         float* __restrict__ z_sc, float* __restrict__ z_qc,           // next-parity stats
         const float* __restrict__ X,
         const float* __restrict__ g_u, const float* __restrict__ be_u,
         const float* __restrict__ g_h, const float* __restrict__ be_h,
         unsigned* __restrict__ ct, int s)
{
    __shared__ __align__(16) f16 smem[2][2][64][72];
    __shared__ int lastFlag;
    const int b = blockIdx.x;
    const int m0 = (b >> 4) * 64, n0 = (b & 15) * 64;
    gemm_job<DC, false>(combB_par, DC, Wh16, pre_c, 1024, sc_, qc_,
                        nullptr, nullptr, 0, m0, n0, smem[0], smem[1]);
    const int gid = n0 >> 6;
    __syncthreads();
    if (threadIdx.x == 0) {
        __threadfence();
        unsigned n = __hip_atomic_fetch_add(&ct[gid], 1u, __ATOMIC_ACQ_REL, __HIP_MEMORY_SCOPE_AGENT);
        lastFlag = (n == (unsigned)(s * 8 + 7));
    }
    __syncthreads();
    if (!lastFlag) return;
    __builtin_amdgcn_fence(__ATOMIC_ACQUIRE, "agent");

    // update epilogue for cols n0..n0+63: u, c, h_new -> h32, combA.h; x(s+1) prefetch; stat zero
    const int tid = threadIdx.x;
    const int c4 = (tid & 15) * 4;
    const int rb = tid >> 4;
    float muU[4], rqU[4], gU[4], bU[4], muC[4], rqC[4], gH[4], bH[4];
#pragma unroll
    for (int q = 0; q < 4; ++q) {
        const int col = n0 + c4 + q;
        float m1 = su[col] * (1.0f / 512.0f);
        float v1 = fmaxf(qu[col] * (1.0f / 512.0f) - m1 * m1, 0.f);
        muU[q] = m1; rqU[q] = rsqrtf(v1 + EPSV); gU[q] = g_u[col]; bU[q] = be_u[col];
        float m2 = sc_[col] * (1.0f / 512.0f);
        float v2 = fmaxf(qc_[col] * (1.0f / 512.0f) - m2 * m2, 0.f);
        muC[q] = m2; rqC[q] = rsqrtf(v2 + EPSV); gH[q] = g_h[col]; bH[q] = be_h[col];
    }
    const bool doX = (n0 + c4 < NIN) && (s + 1 < SS);
#pragma unroll 2
    for (int rr = 0; rr < 16; ++rr) {
        const int row = rb + rr * 32;
        f32x4 pu = *(const f32x4*)(pre_ur + (size_t)row * 2048 + n0 + c4);
        f32x4 pc = *(const f32x4*)(pre_c + (size_t)row * 1024 + n0 + c4);
        f32x4 h  = *(const f32x4*)(h32 + (size_t)row * 1024 + n0 + c4);
        f32x4 hn; f16x4 o;
#pragma unroll
        for (int q = 0; q < 4; ++q) {
            float u = sigmoid_(gU[q] * ((pu[q] - muU[q]) * rqU[q]) + bU[q]);
            float c = tanh_(gH[q] * ((pc[q] - muC[q]) * rqC[q]) + bH[q]);
            float hv = (1.f - u) * c + u * h[q];
            hn[q] = hv; o[q] = (f16)hv;
        }
        *(f32x4*)(h32 + (size_t)row * 1024 + n0 + c4) = hn;
        *(f16x4*)(combA + (size_t)row * DC + NIN + n0 + c4) = o;
        if (doX) {
            f32x4 xv = *(const f32x4*)(X + (size_t)row * SS * NIN + (size_t)(s + 1) * NIN + n0 + c4);
            f16x4 xo;
#pragma unroll
            for (int q = 0; q < 4; ++q) xo[q] = (f16)xv[q];
            *(f16x4*)(combA + (size_t)row * DC + n0 + c4) = xo;
            *(f16x4*)(combB_nxt + (size_t)row * DC + n0 + c4) = xo;
        }
    }
    if (tid < 128) { z_su[gid * 128 + tid] = 0.f; z_qu[gid * 128 + tid] = 0.f; }
    if (tid < 64)  { z_sc[gid * 64 + tid] = 0.f;  z_qc[gid * 64 + tid] = 0.f; }
}

// ---------------- final o for s = 255 ----------------
__global__ __launch_bounds__(512, 2)
void k_o16(const f16* __restrict__ combA, const f16* __restrict__ Wo16,
           const float* __restrict__ b_o, float* __restrict__ outp)
{
    __shared__ __align__(16) f16 smem[2][2][64][72];
    const int b = blockIdx.x;
    const int m0 = (b >> 1) * 64, n0 = (b & 1) * 64;
    gemm_job<DH, true>(combA + NIN, DC, Wo16, nullptr, 0, nullptr, nullptr,
                       b_o, outp, SS - 1, m0, n0, smem[0], smem[1]);
}

// ---------------- host launch ----------------
extern "C" void kernel_launch(void* const* d_in, const int* in_sizes, int n_in,
                              void* d_out, int out_size, void* d_ws, size_t ws_size,
                              hipStream_t stream)
{
    const float* X    = (const float*)d_in[0];
    const float* W_u  = (const float*)d_in[1];
    const float* W_r  = (const float*)d_in[3];
    const float* W_h  = (const float*)d_in[5];
    const float* W_o  = (const float*)d_in[7];
    const float* b_o  = (const float*)d_in[8];
    const float* g_u  = (const float*)d_in[9];
    const float* be_u = (const float*)d_in[10];
    const float* g_r  = (const float*)d_in[11];
    const float* be_r = (const float*)d_in[12];
    const float* g_h  = (const float*)d_in[13];
    const float* be_h = (const float*)d_in[14];
    float* out = (float*)d_out;

    char* p = (char*)d_ws;
    auto alloc = [&](size_t bytes) { char* r = p; p += (bytes + 255) & ~(size_t)255; return r; };
    f16*   combA   = (f16*)alloc((size_t)BB * DC * 2);
    f16*   combB   = (f16*)alloc((size_t)2 * BB * DC * 2);   // parity double-buffer
    f16*   Wur     = (f16*)alloc((size_t)2048 * DC * 2);
    f16*   Wh16    = (f16*)alloc((size_t)DH * DC * 2);
    f16*   Wo16    = (f16*)alloc((size_t)NOUT * DH * 2);
    float* pre_ur  = (float*)alloc((size_t)BB * 2048 * 4);
    float* pre_c   = (float*)alloc((size_t)BB * DH * 4);
    float* h32     = (float*)alloc((size_t)BB * DH * 4);
    float* ssum_ur = (float*)alloc(2 * 2048 * 4);
    float* ssq_ur  = (float*)alloc(2 * 2048 * 4);
    float* ssum_c  = (float*)alloc(2 * 1024 * 4);
    float* ssq_c   = (float*)alloc(2 * 1024 * 4);
    unsigned* urt  = (unsigned*)alloc(16 * 4);
    unsigned* ct   = (unsigned*)alloc(16 * 4);

    k_convert<<<1024, 256, 0, stream>>>(W_u, W_r, W_h, W_o, Wur, Wh16, Wo16);
    k_init<<<1024, 256, 0, stream>>>(X, combA, combB, h32,
                                     ssum_ur, ssq_ur, ssum_c, ssq_c, urt, ct);

    for (int s = 0; s < SS; ++s) {
        const int par = s & 1, nxt = 1 - par;
        // launch 1: o(s-1) || pre_ur = combA @ Wur^T (+stats); last r-block per group: gate
        k_uro<<<272, 512, 0, stream>>>(combA, Wur, Wo16, pre_ur,
                                       ssum_ur + par * 2048, ssq_ur + par * 2048,
                                       combB + (size_t)par * BB * DC, h32,
                                       g_r, be_r, b_o, out, urt, s);
        // launch 2: pre_c = combB[par] @ Wh^T (+stats); last block per group: update epilogue
        k_c<<<128, 512, 0, stream>>>(combB + (size_t)par * BB * DC, Wh16,
                                     pre_c, ssum_c + par * 1024, ssq_c + par * 1024,
                                     pre_ur, ssum_ur + par * 2048, ssq_ur + par * 2048,
                                     h32, combA, combB + (size_t)nxt * BB * DC,
                                     ssum_ur + nxt * 2048, ssq_ur + nxt * 2048,
                                     ssum_c + nxt * 1024, ssq_c + nxt * 1024,
                                     X, g_u, be_u, g_h, be_h, ct, s);
    }
    // final o for s = 255 (combA h-region holds h_new(255))
    k_o16<<<16, 512, 0, stream>>>(combA, Wo16, b_o, out);
}